// Round 3
// baseline (753.821 us; speedup 1.0000x reference)
//
#include <hip/hip_runtime.h>
#include <hip/hip_bf16.h>

#define DD 64
#define LATENT 32
#define OUTD 64
#define SCAN_TILE 1024   // items per block in the scan (256 thr x 4)

// ---------------------------------------------------------------------------
// 1) Histogram: counts[r] = #edges received by node r.
// ---------------------------------------------------------------------------
__global__ __launch_bounds__(256) void hist_kernel(
    const int* __restrict__ recv, int* __restrict__ counts, int nEdges)
{
    int e = blockIdx.x * 256 + threadIdx.x;
    if (e < nEdges) atomicAdd(&counts[recv[e]], 1);
}

// ---------------------------------------------------------------------------
// 2a) Scan pass 1: per-block (1024 items) reduction -> bsum[block]
// ---------------------------------------------------------------------------
__global__ __launch_bounds__(256) void scan_reduce_kernel(
    const int* __restrict__ counts, int* __restrict__ bsum, int n)
{
    __shared__ int l[256];
    int tid = threadIdx.x;
    int base = blockIdx.x * SCAN_TILE + tid * 4;
    int s = 0;
#pragma unroll
    for (int i = 0; i < 4; ++i)
        if (base + i < n) s += counts[base + i];
    l[tid] = s;
    __syncthreads();
    for (int d = 128; d > 0; d >>= 1) {
        if (tid < d) l[tid] += l[tid + d];
        __syncthreads();
    }
    if (tid == 0) bsum[blockIdx.x] = l[0];
}

// ---------------------------------------------------------------------------
// 2b) Scan pass 2: exclusive scan of bsum[nb] in one block (nb <= 256)
// ---------------------------------------------------------------------------
__global__ __launch_bounds__(256) void scan_blocks_kernel(
    int* __restrict__ bsum, int nb)
{
    __shared__ int sc[2][256];
    int tid = threadIdx.x;
    int v = (tid < nb) ? bsum[tid] : 0;
    int orig = v;
    sc[0][tid] = v;
    __syncthreads();
    int src = 0;
#pragma unroll
    for (int d = 1; d < 256; d <<= 1) {
        int x = sc[src][tid];
        if (tid >= d) x += sc[src][tid - d];
        sc[src ^ 1][tid] = x;
        src ^= 1;
        __syncthreads();
    }
    if (tid < nb) bsum[tid] = sc[src][tid] - orig;   // exclusive
}

// ---------------------------------------------------------------------------
// 2c) Scan pass 3: per-block exclusive scan + block offset -> offsets, cursor
// ---------------------------------------------------------------------------
__global__ __launch_bounds__(256) void scan_final_kernel(
    const int* __restrict__ counts, const int* __restrict__ bsum,
    int* __restrict__ offsets, int* __restrict__ cursor, int n)
{
    __shared__ int sc[2][256];
    int tid = threadIdx.x;
    int base = blockIdx.x * SCAN_TILE + tid * 4;
    int c[4];
    int s = 0;
#pragma unroll
    for (int i = 0; i < 4; ++i) {
        c[i] = (base + i < n) ? counts[base + i] : 0;
        s += c[i];
    }
    sc[0][tid] = s;
    __syncthreads();
    int src = 0;
#pragma unroll
    for (int d = 1; d < 256; d <<= 1) {
        int x = sc[src][tid];
        if (tid >= d) x += sc[src][tid - d];
        sc[src ^ 1][tid] = x;
        src ^= 1;
        __syncthreads();
    }
    int run = bsum[blockIdx.x] + sc[src][tid] - s;   // exclusive prefix
#pragma unroll
    for (int i = 0; i < 4; ++i) {
        if (base + i < n) {
            offsets[base + i] = run;
            cursor[base + i]  = run;
        }
        run += c[i];
    }
}

// ---------------------------------------------------------------------------
// 3) Place edges into CSR buckets.
// ---------------------------------------------------------------------------
__global__ __launch_bounds__(256) void place_kernel(
    const int* __restrict__ recv, int* __restrict__ cursor,
    int* __restrict__ edge_ids, int nEdges)
{
    int e = blockIdx.x * 256 + threadIdx.x;
    if (e < nEdges) {
        int r = recv[e];
        int idx = atomicAdd(&cursor[r], 1);
        edge_ids[idx] = e;
    }
}

// ---------------------------------------------------------------------------
// 4) Gather: one wave per node, lane = feature. start/cnt forced scalar so
//    edge_ids loads become s_load and row loads are saddr-form with 4 rows
//    in flight. Mean written into d_out rows (reused as scratch; safe: mlp
//    reads row n only from the threads that later overwrite it).
// ---------------------------------------------------------------------------
__global__ __launch_bounds__(256) void gather_kernel(
    const float* __restrict__ edge_attr,   // [nEdges*64]
    const int*   __restrict__ edge_ids,    // [nEdges] CSR order
    const int*   __restrict__ offsets,     // [nNodes]
    const int*   __restrict__ counts,      // [nNodes]
    float*       __restrict__ mean_out,    // [nNodes*64]
    int nNodes)
{
    int node = (blockIdx.x * 256 + threadIdx.x) >> 6;
    int lane = threadIdx.x & 63;
    if (node >= nNodes) return;
    int start = __builtin_amdgcn_readfirstlane(offsets[node]);
    int cnt   = __builtin_amdgcn_readfirstlane(counts[node]);

    float s0 = 0.0f, s1 = 0.0f, s2 = 0.0f, s3 = 0.0f;
    int i = 0;
    for (; i + 4 <= cnt; i += 4) {
        int e0 = edge_ids[start + i];
        int e1 = edge_ids[start + i + 1];
        int e2 = edge_ids[start + i + 2];
        int e3 = edge_ids[start + i + 3];
        s0 += edge_attr[(size_t)e0 * DD + lane];
        s1 += edge_attr[(size_t)e1 * DD + lane];
        s2 += edge_attr[(size_t)e2 * DD + lane];
        s3 += edge_attr[(size_t)e3 * DD + lane];
    }
    for (; i < cnt; ++i)
        s0 += edge_attr[(size_t)edge_ids[start + i] * DD + lane];

    float inv = 1.0f / (float)max(cnt, 1);
    mean_out[(size_t)node * DD + lane] = ((s0 + s1) + (s2 + s3)) * inv;
}

// ---------------------------------------------------------------------------
// 5) MLP: TWO threads per node (halves the latency exposure: 3125 waves vs
//    1562). Thread part p in {0,1} accumulates half of the 192-dim dot:
//      p=0: node_attr[0..63]   (W1 rows   0..63) + global[0..31] (rows 128..159)
//      p=1: mean[0..63]        (W1 rows  64..127) + global[32..63] (rows 160..191)
//    Partial h exchanged through LDS (pad 33 -> conflict-free), then part p
//    computes outputs [32p, 32p+32).
// ---------------------------------------------------------------------------
__global__ __launch_bounds__(256) void mlp_kernel(
    const float* __restrict__ node_attr,   // [nNodes*64]
    const float* __restrict__ global_attr, // [nBatch*64]
    const int*   __restrict__ ng_index,    // [nNodes]
    const float* __restrict__ W1,          // [192*32]
    const float* __restrict__ b1,          // [32]
    const float* __restrict__ W2,          // [32*64]
    const float* __restrict__ b2,          // [64]
    float*                    io,          // [nNodes*64] mean in, out out
    int nNodes)
{
    __shared__ float part[256 * 33];

    const int tid = threadIdx.x;
    const int p   = tid & 1;                       // which half
    const int n   = blockIdx.x * 128 + (tid >> 1); // node
    const bool live = (n < nNodes);

    float h[LATENT];
#pragma unroll
    for (int j = 0; j < LATENT; ++j) h[j] = 0.0f;

    if (live) {
        const int g = ng_index[n];
        // main segment: p=0 -> node_attr row (W1 rows 0..63)
        //               p=1 -> mean row      (W1 rows 64..127)
        const float4* amain = (const float4*)((p == 0 ? node_attr : io) + (size_t)n * DD);
        const float*  wmain = W1 + (p * DD) * LATENT;
#pragma unroll
        for (int kk = 0; kk < 16; ++kk) {
            float4 v = amain[kk];
            const float* w = wmain + (kk * 4) * LATENT;
#pragma unroll
            for (int j = 0; j < LATENT; ++j)
                h[j] = fmaf(v.x, w[j],
                       fmaf(v.y, w[LATENT + j],
                       fmaf(v.z, w[2 * LATENT + j],
                       fmaf(v.w, w[3 * LATENT + j], h[j]))));
        }
        // global segment half: p=0 -> cols 0..31 (rows 128..159)
        //                      p=1 -> cols 32..63 (rows 160..191)
        const float4* aglob = (const float4*)(global_attr + (size_t)g * DD + p * 32);
        const float*  wglob = W1 + (2 * DD + p * 32) * LATENT;
#pragma unroll
        for (int kk = 0; kk < 8; ++kk) {
            float4 v = aglob[kk];
            const float* w = wglob + (kk * 4) * LATENT;
#pragma unroll
            for (int j = 0; j < LATENT; ++j)
                h[j] = fmaf(v.x, w[j],
                       fmaf(v.y, w[LATENT + j],
                       fmaf(v.z, w[2 * LATENT + j],
                       fmaf(v.w, w[3 * LATENT + j], h[j]))));
        }
    }

    // exchange partials: h_full = mine + partner's (+ b1), then ReLU
    float* my = part + tid * 33;
#pragma unroll
    for (int j = 0; j < LATENT; ++j) my[j] = h[j];
    __syncthreads();
    const float* other = part + (tid ^ 1) * 33;
#pragma unroll
    for (int j = 0; j < LATENT; ++j)
        h[j] = fmaxf(h[j] + other[j] + b1[j], 0.0f);

    if (!live) return;

    // layer 2: this thread produces outputs [32p, 32p+32)
    const int c0 = p * 32;
    float o[32];
#pragma unroll
    for (int t = 0; t < 32; ++t) o[t] = b2[c0 + t];
    for (int j = 0; j < LATENT; ++j) {
        const float hj = h[j];
        const float* w = W2 + j * OUTD + c0;
#pragma unroll
        for (int t = 0; t < 32; ++t) o[t] = fmaf(hj, w[t], o[t]);
    }

    float4* outp = (float4*)(io + (size_t)n * OUTD + c0);
#pragma unroll
    for (int q = 0; q < 8; ++q)
        outp[q] = make_float4(o[4*q], o[4*q+1], o[4*q+2], o[4*q+3]);
}

extern "C" void kernel_launch(void* const* d_in, const int* in_sizes, int n_in,
                              void* d_out, int out_size, void* d_ws, size_t ws_size,
                              hipStream_t stream)
{
    const float* node_attr   = (const float*)d_in[0];
    const float* edge_attr   = (const float*)d_in[1];
    const float* global_attr = (const float*)d_in[2];
    const float* W1          = (const float*)d_in[3];
    const float* b1          = (const float*)d_in[4];
    const float* W2          = (const float*)d_in[5];
    const float* b2          = (const float*)d_in[6];
    const int*   recv        = (const int*)d_in[7];
    const int*   ng_index    = (const int*)d_in[8];
    float*       out         = (float*)d_out;

    const int nNodes = in_sizes[0] / DD;
    const int nEdges = in_sizes[1] / DD;
    const int nb     = (nNodes + SCAN_TILE - 1) / SCAN_TILE;   // 98 blocks

    // ws layout (ints): counts[n] | offsets[n] | cursor[n] | bsum[256] | edge_ids[nEdges]
    int* counts   = (int*)d_ws;
    int* offsets  = counts  + nNodes;
    int* cursor   = offsets + nNodes;
    int* bsum     = cursor  + nNodes;
    int* edge_ids = bsum    + 256;

    hipMemsetAsync(counts, 0, (size_t)nNodes * sizeof(int), stream);

    hist_kernel<<<(nEdges + 255) / 256, 256, 0, stream>>>(recv, counts, nEdges);
    scan_reduce_kernel<<<nb, 256, 0, stream>>>(counts, bsum, nNodes);
    scan_blocks_kernel<<<1, 256, 0, stream>>>(bsum, nb);
    scan_final_kernel<<<nb, 256, 0, stream>>>(counts, bsum, offsets, cursor, nNodes);
    place_kernel<<<(nEdges + 255) / 256, 256, 0, stream>>>(recv, cursor, edge_ids, nEdges);

    gather_kernel<<<(nNodes + 3) / 4, 256, 0, stream>>>(
        edge_attr, edge_ids, offsets, counts, out, nNodes);

    mlp_kernel<<<(nNodes + 127) / 128, 256, 0, stream>>>(
        node_attr, global_attr, ng_index, W1, b1, W2, b2, out, nNodes);
}

// Round 4
// 611.588 us; speedup vs baseline: 1.2326x; 1.2326x over previous
//
#include <hip/hip_runtime.h>
#include <hip/hip_bf16.h>

#define DD 64
#define LATENT 32
#define OUTD 64
#define SCAN_TILE 1024   // items per block in the scan (256 thr x 4)

// ---------------------------------------------------------------------------
// 1) Histogram: counts[r] = #edges received by node r.
// ---------------------------------------------------------------------------
__global__ __launch_bounds__(256) void hist_kernel(
    const int* __restrict__ recv, int* __restrict__ counts, int nEdges)
{
    int e = blockIdx.x * 256 + threadIdx.x;
    if (e < nEdges) atomicAdd(&counts[recv[e]], 1);
}

// ---------------------------------------------------------------------------
// 2a) Scan pass 1: per-block (1024 items) reduction -> bsum[block]
// ---------------------------------------------------------------------------
__global__ __launch_bounds__(256) void scan_reduce_kernel(
    const int* __restrict__ counts, int* __restrict__ bsum, int n)
{
    __shared__ int l[256];
    int tid = threadIdx.x;
    int base = blockIdx.x * SCAN_TILE + tid * 4;
    int s = 0;
#pragma unroll
    for (int i = 0; i < 4; ++i)
        if (base + i < n) s += counts[base + i];
    l[tid] = s;
    __syncthreads();
    for (int d = 128; d > 0; d >>= 1) {
        if (tid < d) l[tid] += l[tid + d];
        __syncthreads();
    }
    if (tid == 0) bsum[blockIdx.x] = l[0];
}

// ---------------------------------------------------------------------------
// 2b) Scan pass 2: exclusive scan of bsum[nb] in one block (nb <= 256)
// ---------------------------------------------------------------------------
__global__ __launch_bounds__(256) void scan_blocks_kernel(
    int* __restrict__ bsum, int nb)
{
    __shared__ int sc[2][256];
    int tid = threadIdx.x;
    int v = (tid < nb) ? bsum[tid] : 0;
    int orig = v;
    sc[0][tid] = v;
    __syncthreads();
    int src = 0;
#pragma unroll
    for (int d = 1; d < 256; d <<= 1) {
        int x = sc[src][tid];
        if (tid >= d) x += sc[src][tid - d];
        sc[src ^ 1][tid] = x;
        src ^= 1;
        __syncthreads();
    }
    if (tid < nb) bsum[tid] = sc[src][tid] - orig;   // exclusive
}

// ---------------------------------------------------------------------------
// 2c) Scan pass 3: per-block exclusive scan + block offset -> offsets, cursor
// ---------------------------------------------------------------------------
__global__ __launch_bounds__(256) void scan_final_kernel(
    const int* __restrict__ counts, const int* __restrict__ bsum,
    int* __restrict__ offsets, int* __restrict__ cursor, int n)
{
    __shared__ int sc[2][256];
    int tid = threadIdx.x;
    int base = blockIdx.x * SCAN_TILE + tid * 4;
    int c[4];
    int s = 0;
#pragma unroll
    for (int i = 0; i < 4; ++i) {
        c[i] = (base + i < n) ? counts[base + i] : 0;
        s += c[i];
    }
    sc[0][tid] = s;
    __syncthreads();
    int src = 0;
#pragma unroll
    for (int d = 1; d < 256; d <<= 1) {
        int x = sc[src][tid];
        if (tid >= d) x += sc[src][tid - d];
        sc[src ^ 1][tid] = x;
        src ^= 1;
        __syncthreads();
    }
    int run = bsum[blockIdx.x] + sc[src][tid] - s;   // exclusive prefix
#pragma unroll
    for (int i = 0; i < 4; ++i) {
        if (base + i < n) {
            offsets[base + i] = run;
            cursor[base + i]  = run;
        }
        run += c[i];
    }
}

// ---------------------------------------------------------------------------
// 3) Place edges into CSR buckets.
// ---------------------------------------------------------------------------
__global__ __launch_bounds__(256) void place_kernel(
    const int* __restrict__ recv, int* __restrict__ cursor,
    int* __restrict__ edge_ids, int nEdges)
{
    int e = blockIdx.x * 256 + threadIdx.x;
    if (e < nEdges) {
        int r = recv[e];
        int idx = atomicAdd(&cursor[r], 1);
        edge_ids[idx] = e;
    }
}

// ---------------------------------------------------------------------------
// 4) Precompute g1[b][j] = b1[j] + global_attr[b] . W1[128+k][j]  (64x32).
//    Tiny: 2048 threads, 64 FMA each. Removes the global segment (and b1)
//    from the hot MLP kernel.
// ---------------------------------------------------------------------------
__global__ __launch_bounds__(256) void g1_kernel(
    const float* __restrict__ global_attr,  // [64*64]
    const float* __restrict__ W1,           // [192*32]
    const float* __restrict__ b1,           // [32]
    float*       __restrict__ g1,           // [64*32]
    int nBatch)
{
    int t = blockIdx.x * 256 + threadIdx.x;
    int b = t >> 5;
    int j = t & 31;
    if (b >= nBatch) return;
    float acc = b1[j];
    const float* g = global_attr + (size_t)b * DD;
    const float* w = W1 + 128 * LATENT + j;
    for (int k = 0; k < DD; ++k)
        acc = fmaf(g[k], w[k * LATENT], acc);
    g1[b * LATENT + j] = acc;
}

// ---------------------------------------------------------------------------
// 5) Gather: one wave per node, lane = feature; mean -> d_out rows (scratch).
// ---------------------------------------------------------------------------
__global__ __launch_bounds__(256) void gather_kernel(
    const float* __restrict__ edge_attr,   // [nEdges*64]
    const int*   __restrict__ edge_ids,    // [nEdges] CSR order
    const int*   __restrict__ offsets,     // [nNodes]
    const int*   __restrict__ counts,      // [nNodes]
    float*       __restrict__ mean_out,    // [nNodes*64]
    int nNodes)
{
    int node = (blockIdx.x * 256 + threadIdx.x) >> 6;
    int lane = threadIdx.x & 63;
    if (node >= nNodes) return;
    int start = __builtin_amdgcn_readfirstlane(offsets[node]);
    int cnt   = __builtin_amdgcn_readfirstlane(counts[node]);

    float s0 = 0.0f, s1 = 0.0f, s2 = 0.0f, s3 = 0.0f;
    int i = 0;
    for (; i + 4 <= cnt; i += 4) {
        int e0 = edge_ids[start + i];
        int e1 = edge_ids[start + i + 1];
        int e2 = edge_ids[start + i + 2];
        int e3 = edge_ids[start + i + 3];
        s0 += edge_attr[(size_t)e0 * DD + lane];
        s1 += edge_attr[(size_t)e1 * DD + lane];
        s2 += edge_attr[(size_t)e2 * DD + lane];
        s3 += edge_attr[(size_t)e3 * DD + lane];
    }
    for (; i < cnt; ++i)
        s0 += edge_attr[(size_t)edge_ids[start + i] * DD + lane];

    float inv = 1.0f / (float)max(cnt, 1);
    mean_out[(size_t)node * DD + lane] = ((s0 + s1) + (s2 + s3)) * inv;
}

// ---------------------------------------------------------------------------
// 6) MLP: wave-pair per 64 nodes. Wave p in {0,1} is WAVE-uniform, so weight
//    addresses stay wave-uniform -> s_load (the R3 bug was p per-lane).
//      p=0: node_attr row . W1 rows [0,64)   + h init = g1[ng_index[n]]
//      p=1: mean row      . W1 rows [64,128) + h init = 0
//    Partial h exchanged through LDS in [j][lane] layout (lane-consecutive,
//    conflict-free). Layer 2: wave p produces outputs [32p, 32p+32).
//    Block = 256 thr = 4 waves = 2 pairs = 128 nodes. 3125 waves total.
// ---------------------------------------------------------------------------
__global__ __launch_bounds__(256, 3) void mlp_kernel(
    const float* __restrict__ node_attr,   // [nNodes*64]
    const int*   __restrict__ ng_index,    // [nNodes]
    const float* __restrict__ W1,          // [192*32]
    const float* __restrict__ W2,          // [32*64]
    const float* __restrict__ b2,          // [64]
    const float* __restrict__ g1,          // [64*32] precomputed global proj
    float*                    io,          // [nNodes*64] mean in, out out
    int nNodes)
{
    __shared__ float xch[2 * 2 * LATENT * 64];   // [pair][p][j][lane] 32 KB

    const int tid  = threadIdx.x;
    const int wave = tid >> 6;
    const int lane = tid & 63;
    const int pair = wave >> 1;
    const int p    = wave & 1;                   // wave-uniform!
    const int n    = blockIdx.x * 128 + pair * 64 + lane;
    const bool live = (n < nNodes);

    float h[LATENT];
#pragma unroll
    for (int j = 0; j < LATENT; ++j) h[j] = 0.0f;

    if (live) {
        // hoist the whole input row into registers (16 independent loads)
        const float4* a = (const float4*)((p == 0 ? node_attr : io) + (size_t)n * DD);
        float4 xv[16];
#pragma unroll
        for (int kk = 0; kk < 16; ++kk) xv[kk] = a[kk];

        if (p == 0) {
            const int g = ng_index[n];
            const float4* gp = (const float4*)(g1 + g * LATENT);
#pragma unroll
            for (int q = 0; q < 8; ++q) {
                float4 gv = gp[q];
                h[4 * q + 0] = gv.x; h[4 * q + 1] = gv.y;
                h[4 * q + 2] = gv.z; h[4 * q + 3] = gv.w;
            }
        }

        const float* wmain = W1 + (p * DD) * LATENT;   // wave-uniform
#pragma unroll
        for (int kk = 0; kk < 16; ++kk) {
            float4 v = xv[kk];
            const float* w = wmain + (kk * 4) * LATENT;
#pragma unroll
            for (int j = 0; j < LATENT; ++j)
                h[j] = fmaf(v.x, w[j],
                       fmaf(v.y, w[LATENT + j],
                       fmaf(v.z, w[2 * LATENT + j],
                       fmaf(v.w, w[3 * LATENT + j], h[j]))));
        }
    }

    // exchange partial h with partner wave ([j][lane]: lane-consecutive)
    {
        float* dst = xch + ((pair * 2 + p) * LATENT) * 64 + lane;
#pragma unroll
        for (int j = 0; j < LATENT; ++j) dst[j * 64] = h[j];
    }
    __syncthreads();
    if (!live) return;
    {
        const float* src = xch + ((pair * 2 + (1 - p)) * LATENT) * 64 + lane;
#pragma unroll
        for (int j = 0; j < LATENT; ++j)
            h[j] = fmaxf(h[j] + src[j * 64], 0.0f);   // + partner, ReLU
    }

    // layer 2: this wave produces outputs [32p, 32p+32)
    const int c0 = p * 32;
    float o[32];
#pragma unroll
    for (int t = 0; t < 32; ++t) o[t] = b2[c0 + t];
    for (int j = 0; j < LATENT; ++j) {
        const float hj = h[j];
        const float* w = W2 + j * OUTD + c0;          // wave-uniform
#pragma unroll
        for (int t = 0; t < 32; ++t) o[t] = fmaf(hj, w[t], o[t]);
    }

    float4* outp = (float4*)(io + (size_t)n * OUTD + c0);
#pragma unroll
    for (int q = 0; q < 8; ++q)
        outp[q] = make_float4(o[4*q], o[4*q+1], o[4*q+2], o[4*q+3]);
}

extern "C" void kernel_launch(void* const* d_in, const int* in_sizes, int n_in,
                              void* d_out, int out_size, void* d_ws, size_t ws_size,
                              hipStream_t stream)
{
    const float* node_attr   = (const float*)d_in[0];
    const float* edge_attr   = (const float*)d_in[1];
    const float* global_attr = (const float*)d_in[2];
    const float* W1          = (const float*)d_in[3];
    const float* b1          = (const float*)d_in[4];
    const float* W2          = (const float*)d_in[5];
    const float* b2          = (const float*)d_in[6];
    const int*   recv        = (const int*)d_in[7];
    const int*   ng_index    = (const int*)d_in[8];
    float*       out         = (float*)d_out;

    const int nNodes = in_sizes[0] / DD;
    const int nEdges = in_sizes[1] / DD;
    const int nBatch = in_sizes[2] / DD;
    const int nb     = (nNodes + SCAN_TILE - 1) / SCAN_TILE;   // 98 blocks

    // ws layout: counts[n] | offsets[n] | cursor[n] | bsum[256] | edge_ids[nE] | g1[64*32]f
    int* counts   = (int*)d_ws;
    int* offsets  = counts  + nNodes;
    int* cursor   = offsets + nNodes;
    int* bsum     = cursor  + nNodes;
    int* edge_ids = bsum    + 256;
    float* g1     = (float*)(edge_ids + nEdges);

    hipMemsetAsync(counts, 0, (size_t)nNodes * sizeof(int), stream);

    hist_kernel<<<(nEdges + 255) / 256, 256, 0, stream>>>(recv, counts, nEdges);
    scan_reduce_kernel<<<nb, 256, 0, stream>>>(counts, bsum, nNodes);
    scan_blocks_kernel<<<1, 256, 0, stream>>>(bsum, nb);
    scan_final_kernel<<<nb, 256, 0, stream>>>(counts, bsum, offsets, cursor, nNodes);
    place_kernel<<<(nEdges + 255) / 256, 256, 0, stream>>>(recv, cursor, edge_ids, nEdges);

    g1_kernel<<<(nBatch * LATENT + 255) / 256, 256, 0, stream>>>(
        global_attr, W1, b1, g1, nBatch);

    gather_kernel<<<(nNodes + 3) / 4, 256, 0, stream>>>(
        edge_attr, edge_ids, offsets, counts, out, nNodes);

    mlp_kernel<<<(nNodes + 127) / 128, 256, 0, stream>>>(
        node_attr, ng_index, W1, W2, b2, g1, out, nNodes);
}

// Round 5
// 560.884 us; speedup vs baseline: 1.3440x; 1.0904x over previous
//
#include <hip/hip_runtime.h>
#include <hip/hip_bf16.h>

#define DD 64
#define LATENT 32
#define OUTD 64
#define SCAN_TILE 1024   // items per block in the scan (256 thr x 4)

// ---------------------------------------------------------------------------
// 1) Histogram: counts[r] = #edges received by node r.
// ---------------------------------------------------------------------------
__global__ __launch_bounds__(256) void hist_kernel(
    const int* __restrict__ recv, int* __restrict__ counts, int nEdges)
{
    int e = blockIdx.x * 256 + threadIdx.x;
    if (e < nEdges) atomicAdd(&counts[recv[e]], 1);
}

// ---------------------------------------------------------------------------
// 2a) Scan pass 1: per-block (1024 items) reduction -> bsum[block]
// ---------------------------------------------------------------------------
__global__ __launch_bounds__(256) void scan_reduce_kernel(
    const int* __restrict__ counts, int* __restrict__ bsum, int n)
{
    __shared__ int l[256];
    int tid = threadIdx.x;
    int base = blockIdx.x * SCAN_TILE + tid * 4;
    int s = 0;
#pragma unroll
    for (int i = 0; i < 4; ++i)
        if (base + i < n) s += counts[base + i];
    l[tid] = s;
    __syncthreads();
    for (int d = 128; d > 0; d >>= 1) {
        if (tid < d) l[tid] += l[tid + d];
        __syncthreads();
    }
    if (tid == 0) bsum[blockIdx.x] = l[0];
}

// ---------------------------------------------------------------------------
// 2b) Scan pass 2: exclusive scan of bsum[nb] in one block (nb <= 256)
// ---------------------------------------------------------------------------
__global__ __launch_bounds__(256) void scan_blocks_kernel(
    int* __restrict__ bsum, int nb)
{
    __shared__ int sc[2][256];
    int tid = threadIdx.x;
    int v = (tid < nb) ? bsum[tid] : 0;
    int orig = v;
    sc[0][tid] = v;
    __syncthreads();
    int src = 0;
#pragma unroll
    for (int d = 1; d < 256; d <<= 1) {
        int x = sc[src][tid];
        if (tid >= d) x += sc[src][tid - d];
        sc[src ^ 1][tid] = x;
        src ^= 1;
        __syncthreads();
    }
    if (tid < nb) bsum[tid] = sc[src][tid] - orig;   // exclusive
}

// ---------------------------------------------------------------------------
// 2c) Scan pass 3: per-block exclusive scan + block offset -> offsets, cursor
// ---------------------------------------------------------------------------
__global__ __launch_bounds__(256) void scan_final_kernel(
    const int* __restrict__ counts, const int* __restrict__ bsum,
    int* __restrict__ offsets, int* __restrict__ cursor, int n)
{
    __shared__ int sc[2][256];
    int tid = threadIdx.x;
    int base = blockIdx.x * SCAN_TILE + tid * 4;
    int c[4];
    int s = 0;
#pragma unroll
    for (int i = 0; i < 4; ++i) {
        c[i] = (base + i < n) ? counts[base + i] : 0;
        s += c[i];
    }
    sc[0][tid] = s;
    __syncthreads();
    int src = 0;
#pragma unroll
    for (int d = 1; d < 256; d <<= 1) {
        int x = sc[src][tid];
        if (tid >= d) x += sc[src][tid - d];
        sc[src ^ 1][tid] = x;
        src ^= 1;
        __syncthreads();
    }
    int run = bsum[blockIdx.x] + sc[src][tid] - s;   // exclusive prefix
#pragma unroll
    for (int i = 0; i < 4; ++i) {
        if (base + i < n) {
            offsets[base + i] = run;
            cursor[base + i]  = run;
        }
        run += c[i];
    }
}

// ---------------------------------------------------------------------------
// 3) Place edges into CSR buckets.
// ---------------------------------------------------------------------------
__global__ __launch_bounds__(256) void place_kernel(
    const int* __restrict__ recv, int* __restrict__ cursor,
    int* __restrict__ edge_ids, int nEdges)
{
    int e = blockIdx.x * 256 + threadIdx.x;
    if (e < nEdges) {
        int r = recv[e];
        int idx = atomicAdd(&cursor[r], 1);
        edge_ids[idx] = e;
    }
}

// ---------------------------------------------------------------------------
// 4) Precompute g1[b][j] = b1[j] + global_attr[b] . W1[128+k][j]  (64x32).
// ---------------------------------------------------------------------------
__global__ __launch_bounds__(256) void g1_kernel(
    const float* __restrict__ global_attr,  // [64*64]
    const float* __restrict__ W1,           // [192*32]
    const float* __restrict__ b1,           // [32]
    float*       __restrict__ g1,           // [64*32]
    int nBatch)
{
    int t = blockIdx.x * 256 + threadIdx.x;
    int b = t >> 5;
    int j = t & 31;
    if (b >= nBatch) return;
    float acc = b1[j];
    const float* g = global_attr + (size_t)b * DD;
    const float* w = W1 + 128 * LATENT + j;
    for (int k = 0; k < DD; ++k)
        acc = fmaf(g[k], w[k * LATENT], acc);
    g1[b * LATENT + j] = acc;
}

// ---------------------------------------------------------------------------
// 5) Gather: one wave per node, 4 rows per load instruction.
//    Lane = (group g = lane>>4, chunk s = lane&15). One dwordx4 per lane
//    fetches 4 complete 256B rows (1 KB/instr). Edge ids come from a 16B
//    broadcast vector load (no scalar-load chain). Partial sums reduced
//    across the 4 groups with 2 shfl_xor rounds. Mean -> d_out rows.
// ---------------------------------------------------------------------------
__global__ __launch_bounds__(256) void gather_kernel(
    const float* __restrict__ edge_attr,   // [nEdges*64]
    const int*   __restrict__ edge_ids,    // [nEdges] CSR order
    const int*   __restrict__ offsets,     // [nNodes]
    const int*   __restrict__ counts,      // [nNodes]
    float*       __restrict__ mean_out,    // [nNodes*64]
    int nNodes)
{
    int node = (blockIdx.x * 256 + threadIdx.x) >> 6;
    int lane = threadIdx.x & 63;
    if (node >= nNodes) return;
    const int g = lane >> 4;     // which of 4 rows this lane helps load
    const int s = lane & 15;     // 16B chunk within the row

    const int start = offsets[node];
    const int cnt   = counts[node];

    float4 acc = make_float4(0.f, 0.f, 0.f, 0.f);
    for (int i = 0; i < cnt; i += 4) {
        int idx = i + g;
        int id  = edge_ids[start + min(idx, cnt - 1)];   // 4-addr broadcast load
        float4 v = ((const float4*)(edge_attr + (size_t)id * DD))[s];
        float m = (idx < cnt) ? 1.0f : 0.0f;
        acc.x = fmaf(m, v.x, acc.x);
        acc.y = fmaf(m, v.y, acc.y);
        acc.z = fmaf(m, v.z, acc.z);
        acc.w = fmaf(m, v.w, acc.w);
    }
    // sum the 4 groups: xor-16 then xor-32
    acc.x += __shfl_xor(acc.x, 16, 64);
    acc.y += __shfl_xor(acc.y, 16, 64);
    acc.z += __shfl_xor(acc.z, 16, 64);
    acc.w += __shfl_xor(acc.w, 16, 64);
    acc.x += __shfl_xor(acc.x, 32, 64);
    acc.y += __shfl_xor(acc.y, 32, 64);
    acc.z += __shfl_xor(acc.z, 32, 64);
    acc.w += __shfl_xor(acc.w, 32, 64);

    if (g == 0) {
        float inv = 1.0f / (float)max(cnt, 1);
        ((float4*)(mean_out + (size_t)node * DD))[s] =
            make_float4(acc.x * inv, acc.y * inv, acc.z * inv, acc.w * inv);
    }
}

// ---------------------------------------------------------------------------
// 6) MLP: one wave per 64 nodes, LDS-staged inputs, zero strided global ops.
//    Stage 64 rows coalesced (lane=feature) into slab[node][65] (bank-safe
//    both ways: write bank=(r+lane)%32 distinct; read bank=(lane+k)%32,
//    2-way only -> free). Compute lane=node with ds_read_b32 x + wave-uniform
//    scalar weights (1 v_fmac per MAC). Slab reused for the mean segment,
//    then for transposing the output so stores are coalesced too.
//    Wave-synchronous LDS use (in-order DS pipe) -> no barriers needed.
// ---------------------------------------------------------------------------
__global__ __launch_bounds__(128) void mlp_kernel(
    const float* __restrict__ node_attr,   // [nNodes*64]
    const int*   __restrict__ ng_index,    // [nNodes]
    const float* __restrict__ W1,          // [192*32] row-major [k][j]
    const float* __restrict__ W2,          // [32*64]
    const float* __restrict__ b2,          // [64]
    const float* __restrict__ g1,          // [64*32] precomputed global proj
    float*                    io,          // [nNodes*64] mean in, out out
    int nNodes)
{
    __shared__ float slab[2][64 * 65];     // 33.3 KB per 128-thread block

    const int wave = threadIdx.x >> 6;
    const int lane = threadIdx.x & 63;
    const int base = blockIdx.x * 128 + wave * 64;
    if (base >= nNodes) return;            // wave-uniform early out
    const int nvalid = min(64, nNodes - base);
    float* S = slab[wave];

    // h init = g1[ng_index[n]]  (8 KB table, L1-resident)
    float h[LATENT];
    {
        const int n = base + (lane < nvalid ? lane : 0);
        const int g = ng_index[n];
        const float4* gp = (const float4*)(g1 + g * LATENT);
#pragma unroll
        for (int q = 0; q < 8; ++q) {
            float4 gv = gp[q];
            h[4*q+0] = gv.x; h[4*q+1] = gv.y;
            h[4*q+2] = gv.z; h[4*q+3] = gv.w;
        }
    }

    // ---- segment A: node_attr through W1 rows [0,64) ----
#pragma unroll 8
    for (int r = 0; r < nvalid; ++r)
        S[r * 65 + lane] = node_attr[(size_t)(base + r) * DD + lane];
    {
        const float* w = W1;
#pragma unroll 8
        for (int k = 0; k < DD; ++k) {
            float x = S[lane * 65 + k];
            const float* wr = w + k * LATENT;
#pragma unroll
            for (int j = 0; j < LATENT; ++j)
                h[j] = fmaf(x, wr[j], h[j]);
        }
    }

    // ---- segment B: mean rows (from io) through W1 rows [64,128) ----
#pragma unroll 8
    for (int r = 0; r < nvalid; ++r)
        S[r * 65 + lane] = io[(size_t)(base + r) * DD + lane];
    {
        const float* w = W1 + DD * LATENT;
#pragma unroll 8
        for (int k = 0; k < DD; ++k) {
            float x = S[lane * 65 + k];
            const float* wr = w + k * LATENT;
#pragma unroll
            for (int j = 0; j < LATENT; ++j)
                h[j] = fmaf(x, wr[j], h[j]);
        }
    }

    // ReLU
#pragma unroll
    for (int j = 0; j < LATENT; ++j) h[j] = fmaxf(h[j], 0.0f);

    // ---- layer 2: two chunks of 32 outputs, spill transposed into slab ----
#pragma unroll
    for (int c = 0; c < 2; ++c) {
        float o[32];
#pragma unroll
        for (int t = 0; t < 32; ++t) o[t] = b2[c * 32 + t];
        for (int j = 0; j < LATENT; ++j) {
            const float hj = h[j];
            const float* wr = W2 + j * OUTD + c * 32;
#pragma unroll
            for (int t = 0; t < 32; ++t) o[t] = fmaf(hj, wr[t], o[t]);
        }
#pragma unroll
        for (int t = 0; t < 32; ++t) S[lane * 65 + c * 32 + t] = o[t];
    }

    // ---- coalesced store (lane=feature) ----
#pragma unroll 8
    for (int r = 0; r < nvalid; ++r)
        io[(size_t)(base + r) * DD + lane] = S[r * 65 + lane];
}

extern "C" void kernel_launch(void* const* d_in, const int* in_sizes, int n_in,
                              void* d_out, int out_size, void* d_ws, size_t ws_size,
                              hipStream_t stream)
{
    const float* node_attr   = (const float*)d_in[0];
    const float* edge_attr   = (const float*)d_in[1];
    const float* global_attr = (const float*)d_in[2];
    const float* W1          = (const float*)d_in[3];
    const float* b1          = (const float*)d_in[4];
    const float* W2          = (const float*)d_in[5];
    const float* b2          = (const float*)d_in[6];
    const int*   recv        = (const int*)d_in[7];
    const int*   ng_index    = (const int*)d_in[8];
    float*       out         = (float*)d_out;

    const int nNodes = in_sizes[0] / DD;
    const int nEdges = in_sizes[1] / DD;
    const int nBatch = in_sizes[2] / DD;
    const int nb     = (nNodes + SCAN_TILE - 1) / SCAN_TILE;   // 98 blocks

    // ws layout: counts[n] | offsets[n] | cursor[n] | bsum[256] | edge_ids[nE] | g1[64*32]f
    int* counts   = (int*)d_ws;
    int* offsets  = counts  + nNodes;
    int* cursor   = offsets + nNodes;
    int* bsum     = cursor  + nNodes;
    int* edge_ids = bsum    + 256;
    float* g1     = (float*)(edge_ids + nEdges);

    hipMemsetAsync(counts, 0, (size_t)nNodes * sizeof(int), stream);

    hist_kernel<<<(nEdges + 255) / 256, 256, 0, stream>>>(recv, counts, nEdges);
    scan_reduce_kernel<<<nb, 256, 0, stream>>>(counts, bsum, nNodes);
    scan_blocks_kernel<<<1, 256, 0, stream>>>(bsum, nb);
    scan_final_kernel<<<nb, 256, 0, stream>>>(counts, bsum, offsets, cursor, nNodes);
    place_kernel<<<(nEdges + 255) / 256, 256, 0, stream>>>(recv, cursor, edge_ids, nEdges);

    g1_kernel<<<(nBatch * LATENT + 255) / 256, 256, 0, stream>>>(
        global_attr, W1, b1, g1, nBatch);

    gather_kernel<<<(nNodes + 3) / 4, 256, 0, stream>>>(
        edge_attr, edge_ids, offsets, counts, out, nNodes);

    mlp_kernel<<<(nNodes + 127) / 128, 128, 0, stream>>>(
        node_attr, ng_index, W1, W2, b2, g1, out, nNodes);
}